// Round 9
// baseline (100.278 us; speedup 1.0000x reference)
//
#include <hip/hip_runtime.h>
#include <stdint.h>

// SortNode2Pin: per-node argmin over CSR pin slices by sorted_pin_map key.
// v9: 8-bit coarse-key table (8 MB) -> tie prob drops 16x vs 4-bit, killing
// the random exact-key HBM traffic that bounded v8 (~51 MB of random lines).
//  build:  key8[p] = key[p] >> (bits-8)  (NT stream, 16 keys/thread).
//  main:   NPB=512 nodes/block. Phase 1: stage packed (byte<<23|pin) for the
//          block's contiguous slot range into LDS (int4 NT loads, 8 byte-
//          gathers in flight, b128 LDS writes). Phase 2: per-thread branchless
//          3-min scan; unique min byte -> 0 gathers; 2-way tie -> 2 parallel
//          key[] gathers; >=3-way tie (rare) -> short masked loop.

typedef int iv4 __attribute__((ext_vector_type(4)));

#define NPB 512    // nodes per block
#define NT  256    // threads per block
#define CAP 2560   // LDS slot capacity (block range ~2048, sd ~90 -> +5.7 sigma)
#define PINMASK 0x7FFFFFu

__device__ __forceinline__ uint32_t pack4b(iv4 v, int shift) {
    return (((uint32_t)v.x >> shift) & 255u)
         | ((((uint32_t)v.y >> shift) & 255u) << 8)
         | ((((uint32_t)v.z >> shift) & 255u) << 16)
         | ((((uint32_t)v.w >> shift) & 255u) << 24);
}

__global__ void build_key8_kernel(const int* __restrict__ key,
                                  uint8_t* __restrict__ key8,
                                  int num_pins, int shift) {
    int t = blockIdx.x * blockDim.x + threadIdx.x;
    int base = t * 16;
    if (base >= num_pins) return;
    if (base + 16 <= num_pins) {
        const iv4* kp = (const iv4*)(key + base);
        iv4 a = __builtin_nontemporal_load(kp);
        iv4 b = __builtin_nontemporal_load(kp + 1);
        iv4 c = __builtin_nontemporal_load(kp + 2);
        iv4 d = __builtin_nontemporal_load(kp + 3);
        iv4 w;
        w.x = (int)pack4b(a, shift);
        w.y = (int)pack4b(b, shift);
        w.z = (int)pack4b(c, shift);
        w.w = (int)pack4b(d, shift);
        __builtin_nontemporal_store(w, (iv4*)(key8 + base));
    } else {
        for (int j = base; j < num_pins; ++j)
            key8[j] = (uint8_t)(((uint32_t)key[j] >> shift) & 255u);
    }
}

__device__ __forceinline__ uint32_t byte_of(const uint8_t* key8, uint32_t p) {
    return (uint32_t)key8[p];
}

__device__ __forceinline__ iv4 load_chunk(const int* __restrict__ n2p,
                                          int jal, int jbeg, int jend, int c) {
    int j0 = jal + (c << 2);
    if (j0 >= jbeg && j0 + 4 <= jend) {
        return __builtin_nontemporal_load((const iv4*)(n2p + j0));
    }
    iv4 r;
    #pragma unroll
    for (int e = 0; e < 4; ++e) {
        int j = j0 + e;
        r[e] = (j >= jbeg && j < jend) ? __builtin_nontemporal_load(n2p + j)
                                       : -1;   // sentinel -> packs to 0xFFFFFFFF
    }
    return r;
}

__device__ __forceinline__ uint32_t pack_sv(const uint8_t* key8, int pi) {
    if (pi < 0) return 0xFFFFFFFFu;
    uint32_t p = (uint32_t)pi;
    return (byte_of(key8, p) << 23) | p;
}

// branch-free 3-smallest insert
__device__ __forceinline__ void upd3(uint32_t sp, uint32_t& m1, uint32_t& m2,
                                     uint32_t& m3) {
    uint32_t a = min(sp, m1);
    uint32_t b = max(sp, m1);
    uint32_t c = min(b, m2);
    uint32_t d = max(b, m2);
    m1 = a; m2 = c; m3 = min(d, m3);
}

__device__ __forceinline__ int scan_seg3(const uint32_t* slot, int s, int e,
                                         const int* __restrict__ key) {
    if (e <= s) return 0;                      // empty node -> 0
    uint32_t m1 = ~0u, m2 = ~0u, m3 = ~0u;
    for (int q = (s & ~3); q < e; q += 4) {
        iv4 v = *(const iv4*)(slot + q);       // ds_read_b128
        #pragma unroll
        for (int u = 0; u < 4; ++u) {
            int j = q + u;
            uint32_t sp = (uint32_t)v[u];
            sp = (j >= s && j < e) ? sp : ~0u; // mask foreign/pad slots
            upd3(sp, m1, m2, m3);
        }
    }
    uint32_t b1 = m1 >> 23;
    if ((m2 >> 23) != b1) return (int)(m1 & PINMASK);      // unique min byte
    if ((m3 >> 23) != b1) {                                // exactly 2 tied
        int p1 = (int)(m1 & PINMASK), p2 = (int)(m2 & PINMASK);
        int k1 = key[p1], k2 = key[p2];                    // 2 parallel gathers
        return k1 < k2 ? p1 : p2;
    }
    // >=3 tied at min byte (very rare): masked scan with exact keys
    int bk = 0x7fffffff, r = 0;
    for (int q = s; q < e; ++q) {
        uint32_t sp = slot[q];
        if ((sp >> 23) == b1) {
            int p = (int)(sp & PINMASK);
            int k = key[p];
            if (k < bk) { bk = k; r = p; }
        }
    }
    return r;
}

__global__ __launch_bounds__(NT) void SortNode2Pin_stage_kernel(
        const int* __restrict__ starts,
        const int* __restrict__ n2p,
        const int* __restrict__ key,
        const uint8_t* __restrict__ key8,
        int* __restrict__ out,
        int num_nodes) {
    __shared__ __align__(16) uint32_t slot[CAP + 8];

    int t = threadIdx.x;
    int i0 = blockIdx.x * NPB;

    // block slot range (uniform -> scalar loads)
    int iend = i0 + NPB; if (iend > num_nodes) iend = num_nodes;
    int jbeg0 = starts[i0 < num_nodes ? i0 : num_nodes];
    int jend0 = starts[iend];

    // per-thread segment bounds straight from global (L1-served, coalesced)
    int iA = i0 + t;        if (iA > num_nodes) iA = num_nodes;
    int iA1 = iA + 1;       if (iA1 > num_nodes) iA1 = num_nodes;
    int iB = i0 + NT + t;   if (iB > num_nodes) iB = num_nodes;
    int iB1 = iB + 1;       if (iB1 > num_nodes) iB1 = num_nodes;
    int sA = starts[iA], eA = starts[iA1];
    int sB = starts[iB], eB = starts[iB1];

    int range = jend0 - jbeg0;

    if (range <= CAP) {
        // ---- phase 1: cooperative staging, 8 gathers in flight ----------
        int jal = jbeg0 & ~3;
        int nch = (jend0 - jal + 3) >> 2;
        int c = t;
        for (; c + NT < nch; c += 2 * NT) {
            int c2 = c + NT;
            iv4 pa = load_chunk(n2p, jal, jbeg0, jend0, c);
            iv4 pb = load_chunk(n2p, jal, jbeg0, jend0, c2);
            iv4 wa, wb;
            #pragma unroll
            for (int u = 0; u < 4; ++u) wa[u] = (int)pack_sv(key8, pa[u]);
            #pragma unroll
            for (int u = 0; u < 4; ++u) wb[u] = (int)pack_sv(key8, pb[u]);
            *(iv4*)&slot[c  << 2] = wa;
            *(iv4*)&slot[c2 << 2] = wb;
        }
        for (; c < nch; c += NT) {
            iv4 pa = load_chunk(n2p, jal, jbeg0, jend0, c);
            iv4 wa;
            #pragma unroll
            for (int u = 0; u < 4; ++u) wa[u] = (int)pack_sv(key8, pa[u]);
            *(iv4*)&slot[c << 2] = wa;
        }
        __syncthreads();

        // ---- phase 2: branchless 3-min scans ----------------------------
        int ra = scan_seg3(slot, sA - jal, eA - jal, key);
        int rb = scan_seg3(slot, sB - jal, eB - jal, key);
        int na = i0 + t;
        int nb = i0 + NT + t;
        if (na < num_nodes) __builtin_nontemporal_store(ra, out + na);
        if (nb < num_nodes) __builtin_nontemporal_store(rb, out + nb);
    } else {
        // ---- pathological block range: per-thread lazy-tie scan ---------
        for (int idx = t; idx < NPB; idx += NT) {
            int node = i0 + idx;
            if (node >= num_nodes) break;
            int s = starts[node], e = starts[node + 1];
            int mv = 256, bp = 0, bk = -1;
            for (int j = s; j < e; ++j) {
                uint32_t p = (uint32_t)n2p[j];
                int n = (int)byte_of(key8, p);
                if (n > mv) continue;
                if (n < mv) { mv = n; bp = (int)p; bk = -1; }
                else {
                    if (bk < 0) bk = key[bp];
                    int k = key[p];
                    if (k < bk) { bk = k; bp = (int)p; }
                }
            }
            __builtin_nontemporal_store(bp, out + node);
        }
    }
}

// Fallback if workspace too small or pins don't fit the 23-bit packing.
__global__ void SortNode2Pin_direct_kernel(const int* __restrict__ starts,
                                           const int* __restrict__ n2p,
                                           const int* __restrict__ key,
                                           int* __restrict__ out,
                                           int num_nodes) {
    int i = blockIdx.x * blockDim.x + threadIdx.x;
    if (i >= num_nodes) return;
    int s = starts[i];
    int e = starts[i + 1];
    int best_pin = 0;
    int best_key = 0x7fffffff;
    for (int j = s; j < e; ++j) {
        int p = n2p[j];
        int k = key[p];
        if (k < best_key) { best_key = k; best_pin = p; }
    }
    out[i] = best_pin;
}

extern "C" void kernel_launch(void* const* d_in, const int* in_sizes, int n_in,
                              void* d_out, int out_size, void* d_ws, size_t ws_size,
                              hipStream_t stream) {
    const int* starts = (const int*)d_in[0];   // [num_nodes+1]
    const int* n2p    = (const int*)d_in[1];   // [num_pins]
    const int* key    = (const int*)d_in[2];   // [num_pins]
    int num_nodes = out_size;
    int num_pins  = in_sizes[1];

    size_t need = (size_t)((num_pins + 15) / 16) * 16;   // key8 bytes, 16-pad

    if (ws_size >= need && num_pins < (1 << 23)) {
        int bits = 32 - __builtin_clz((unsigned)(num_pins - 1));  // ceil(log2)
        int shift = bits > 8 ? bits - 8 : 0;
        uint8_t* key8 = (uint8_t*)d_ws;

        int g1 = (int)(((size_t)(num_pins + 15) / 16 + NT - 1) / NT);
        build_key8_kernel<<<g1, NT, 0, stream>>>(key, key8, num_pins, shift);

        int g2 = (num_nodes + NPB - 1) / NPB;
        SortNode2Pin_stage_kernel<<<g2, NT, 0, stream>>>(
            starts, n2p, key, key8, (int*)d_out, num_nodes);
    } else {
        int grid = (num_nodes + 255) / 256;
        SortNode2Pin_direct_kernel<<<grid, 256, 0, stream>>>(
            starts, n2p, key, (int*)d_out, num_nodes);
    }
}

// Round 10
// 85.780 us; speedup vs baseline: 1.1690x; 1.1690x over previous
//
#include <hip/hip_runtime.h>
#include <stdint.h>

// SortNode2Pin: per-node argmin over CSR pin slices by sorted_pin_map key.
// v10: v8's 4-bit L2-resident table + deep MLP.
//  - NPB=1024: each thread stages 4 int4 chunks -> 16 key4 gathers in flight
//    (v8 had VGPR_Count=12 => compiler had collapsed MLP to ~2).
//  - Phase 2: compute all 4 segments' 3-mins first (LDS only), then issue all
//    tie gathers together (up to 8 independent masked loads), then resolve.

typedef int iv4 __attribute__((ext_vector_type(4)));

#define NPB 1024   // nodes per block
#define NT  256    // threads per block
#define SEGS 4     // segments per thread
#define CAP 4608   // slots capacity: mean 4096, sd ~128 -> +4 sigma; fallback covers rest
#define PINMASK 0x7FFFFFu

__global__ void build_key4_kernel(const int* __restrict__ key,
                                  uint32_t* __restrict__ key4,
                                  int num_pins, int shift) {
    int t = blockIdx.x * blockDim.x + threadIdx.x;
    int base = t * 8;
    if (base >= num_pins) return;
    if (base + 8 <= num_pins) {
        const iv4* kp = (const iv4*)(key + base);
        iv4 a = __builtin_nontemporal_load(kp);
        iv4 b = __builtin_nontemporal_load(kp + 1);
        uint32_t w = 0;
        w |= (((uint32_t)a.x >> shift) & 15u) << 0;
        w |= (((uint32_t)a.y >> shift) & 15u) << 4;
        w |= (((uint32_t)a.z >> shift) & 15u) << 8;
        w |= (((uint32_t)a.w >> shift) & 15u) << 12;
        w |= (((uint32_t)b.x >> shift) & 15u) << 16;
        w |= (((uint32_t)b.y >> shift) & 15u) << 20;
        w |= (((uint32_t)b.z >> shift) & 15u) << 24;
        w |= (((uint32_t)b.w >> shift) & 15u) << 28;
        __builtin_nontemporal_store(w, key4 + t);
    } else {
        uint32_t w = 0;
        for (int j = 0; base + j < num_pins; ++j) {
            uint32_t k = (uint32_t)key[base + j];
            w |= ((k >> shift) & 15u) << (4 * j);
        }
        __builtin_nontemporal_store(w, key4 + t);
    }
}

__device__ __forceinline__ uint32_t nib_of(const uint32_t* key4, uint32_t p) {
    uint32_t w = key4[p >> 3];
    return (w >> ((p & 7u) * 4u)) & 15u;
}

__device__ __forceinline__ iv4 load_chunk(const int* __restrict__ n2p,
                                          int jal, int jbeg, int jend, int c) {
    int j0 = jal + (c << 2);
    if (j0 >= jbeg && j0 + 4 <= jend) {
        return __builtin_nontemporal_load((const iv4*)(n2p + j0));
    }
    iv4 r;
    #pragma unroll
    for (int e = 0; e < 4; ++e) {
        int j = j0 + e;
        r[e] = (j >= jbeg && j < jend) ? __builtin_nontemporal_load(n2p + j)
                                       : -1;   // sentinel -> packs to 0xFFFFFFFF
    }
    return r;
}

__device__ __forceinline__ uint32_t pack_sv(const uint32_t* key4, int pi) {
    if (pi < 0) return 0xFFFFFFFFu;
    uint32_t p = (uint32_t)pi;
    return (nib_of(key4, p) << 23) | p;
}

// branch-free 3-smallest insert
__device__ __forceinline__ void upd3(uint32_t sp, uint32_t& m1, uint32_t& m2,
                                     uint32_t& m3) {
    uint32_t a = min(sp, m1);
    uint32_t b = max(sp, m1);
    uint32_t c = min(b, m2);
    uint32_t d = max(b, m2);
    m1 = a; m2 = c; m3 = min(d, m3);
}

__device__ __forceinline__ void scan_mins(const uint32_t* slot, int s, int e,
                                          uint32_t& m1, uint32_t& m2, uint32_t& m3) {
    m1 = ~0u; m2 = ~0u; m3 = ~0u;
    for (int q = (s & ~3); q < e; q += 4) {
        iv4 v = *(const iv4*)(slot + q);       // ds_read_b128
        #pragma unroll
        for (int u = 0; u < 4; ++u) {
            int j = q + u;
            uint32_t sp = (uint32_t)v[u];
            sp = (j >= s && j < e) ? sp : ~0u; // mask foreign/pad slots
            upd3(sp, m1, m2, m3);
        }
    }
}

__global__ __launch_bounds__(NT) void SortNode2Pin_stage_kernel(
        const int* __restrict__ starts,
        const int* __restrict__ n2p,
        const int* __restrict__ key,
        const uint32_t* __restrict__ key4,
        int* __restrict__ out,
        int num_nodes) {
    __shared__ __align__(16) uint32_t slot[CAP + 8];

    int t = threadIdx.x;
    int i0 = blockIdx.x * NPB;

    // block slot range (uniform -> scalar loads)
    int iend = i0 + NPB; if (iend > num_nodes) iend = num_nodes;
    int jbeg0 = starts[i0 < num_nodes ? i0 : num_nodes];
    int jend0 = starts[iend];
    int range = jend0 - jbeg0;

    // per-thread segment bounds (coalesced, L1-served)
    int sS[SEGS], eS[SEGS];
    #pragma unroll
    for (int k = 0; k < SEGS; ++k) {
        int ia = i0 + k * NT + t;  if (ia > num_nodes) ia = num_nodes;
        int ib = ia + 1;           if (ib > num_nodes) ib = num_nodes;
        sS[k] = starts[ia];
        eS[k] = starts[ib];
    }

    if (range <= CAP) {
        // ---- phase 1: staging, 16 gathers in flight per thread ----------
        int jal = jbeg0 & ~3;
        int nch = (jend0 - jal + 3) >> 2;
        int c = t;
        for (; c + 3 * NT < nch; c += 4 * NT) {
            iv4 p0 = load_chunk(n2p, jal, jbeg0, jend0, c);
            iv4 p1 = load_chunk(n2p, jal, jbeg0, jend0, c + NT);
            iv4 p2 = load_chunk(n2p, jal, jbeg0, jend0, c + 2 * NT);
            iv4 p3 = load_chunk(n2p, jal, jbeg0, jend0, c + 3 * NT);
            iv4 w0, w1, w2, w3;
            #pragma unroll
            for (int u = 0; u < 4; ++u) w0[u] = (int)pack_sv(key4, p0[u]);
            #pragma unroll
            for (int u = 0; u < 4; ++u) w1[u] = (int)pack_sv(key4, p1[u]);
            #pragma unroll
            for (int u = 0; u < 4; ++u) w2[u] = (int)pack_sv(key4, p2[u]);
            #pragma unroll
            for (int u = 0; u < 4; ++u) w3[u] = (int)pack_sv(key4, p3[u]);
            *(iv4*)&slot[(c           ) << 2] = w0;
            *(iv4*)&slot[(c +     NT  ) << 2] = w1;
            *(iv4*)&slot[(c + 2 * NT  ) << 2] = w2;
            *(iv4*)&slot[(c + 3 * NT  ) << 2] = w3;
        }
        for (; c < nch; c += NT) {
            iv4 pa = load_chunk(n2p, jal, jbeg0, jend0, c);
            iv4 wa;
            #pragma unroll
            for (int u = 0; u < 4; ++u) wa[u] = (int)pack_sv(key4, pa[u]);
            *(iv4*)&slot[c << 2] = wa;
        }
        __syncthreads();

        // ---- phase 2a: 3-min scans for all 4 segments (LDS only) --------
        uint32_t M1[SEGS], M2[SEGS], M3[SEGS];
        #pragma unroll
        for (int k = 0; k < SEGS; ++k)
            scan_mins(slot, sS[k] - jal, eS[k] - jal, M1[k], M2[k], M3[k]);

        // ---- phase 2b: classify; batch tie gathers ----------------------
        int res[SEGS];
        int pa[SEGS], pb[SEGS];
        bool two[SEGS], multi[SEGS];
        #pragma unroll
        for (int k = 0; k < SEGS; ++k) {
            two[k] = false; multi[k] = false;
            pa[k] = 0; pb[k] = 0;
            uint32_t b1 = M1[k] >> 23;
            if (eS[k] <= sS[k]) {
                res[k] = 0;                                   // empty node
            } else if ((M2[k] >> 23) != b1) {
                res[k] = (int)(M1[k] & PINMASK);              // unique min nib
            } else if ((M3[k] >> 23) != b1) {
                two[k] = true;                                // exactly 2 tied
                pa[k] = (int)(M1[k] & PINMASK);
                pb[k] = (int)(M2[k] & PINMASK);
                res[k] = 0;
            } else {
                multi[k] = true;                              // >=3 tied (rare)
                res[k] = 0;
            }
        }
        // all tie gathers issued together (independent masked loads)
        int ka[SEGS], kb[SEGS];
        #pragma unroll
        for (int k = 0; k < SEGS; ++k) {
            ka[k] = 0; kb[k] = 0;
            if (two[k]) { ka[k] = key[pa[k]]; kb[k] = key[pb[k]]; }
        }
        #pragma unroll
        for (int k = 0; k < SEGS; ++k)
            if (two[k]) res[k] = ka[k] < kb[k] ? pa[k] : pb[k];

        // ---- phase 2c: >=3-way ties (rare): masked exact scan -----------
        #pragma unroll
        for (int k = 0; k < SEGS; ++k) {
            if (multi[k]) {
                uint32_t b1 = M1[k] >> 23;
                int bk = 0x7fffffff, r = 0;
                for (int q = sS[k] - jal; q < eS[k] - jal; ++q) {
                    uint32_t sp = slot[q];
                    if ((sp >> 23) == b1) {
                        int p = (int)(sp & PINMASK);
                        int kk = key[p];
                        if (kk < bk) { bk = kk; r = p; }
                    }
                }
                res[k] = r;
            }
        }

        // ---- store ------------------------------------------------------
        #pragma unroll
        for (int k = 0; k < SEGS; ++k) {
            int node = i0 + k * NT + t;
            if (node < num_nodes)
                __builtin_nontemporal_store(res[k], out + node);
        }
    } else {
        // ---- pathological block range: per-thread lazy-tie scan ---------
        for (int idx = t; idx < NPB; idx += NT) {
            int node = i0 + idx;
            if (node >= num_nodes) break;
            int s = starts[node], e = starts[node + 1];
            int mv = 16, bp = 0, bk = -1;
            for (int j = s; j < e; ++j) {
                uint32_t p = (uint32_t)n2p[j];
                int n = (int)nib_of(key4, p);
                if (n > mv) continue;
                if (n < mv) { mv = n; bp = (int)p; bk = -1; }
                else {
                    if (bk < 0) bk = key[bp];
                    int k = key[p];
                    if (k < bk) { bk = k; bp = (int)p; }
                }
            }
            __builtin_nontemporal_store(bp, out + node);
        }
    }
}

// Fallback if workspace too small or pins don't fit the 23-bit packing.
__global__ void SortNode2Pin_direct_kernel(const int* __restrict__ starts,
                                           const int* __restrict__ n2p,
                                           const int* __restrict__ key,
                                           int* __restrict__ out,
                                           int num_nodes) {
    int i = blockIdx.x * blockDim.x + threadIdx.x;
    if (i >= num_nodes) return;
    int s = starts[i];
    int e = starts[i + 1];
    int best_pin = 0;
    int best_key = 0x7fffffff;
    for (int j = s; j < e; ++j) {
        int p = n2p[j];
        int k = key[p];
        if (k < best_key) { best_key = k; best_pin = p; }
    }
    out[i] = best_pin;
}

extern "C" void kernel_launch(void* const* d_in, const int* in_sizes, int n_in,
                              void* d_out, int out_size, void* d_ws, size_t ws_size,
                              hipStream_t stream) {
    const int* starts = (const int*)d_in[0];   // [num_nodes+1]
    const int* n2p    = (const int*)d_in[1];   // [num_pins]
    const int* key    = (const int*)d_in[2];   // [num_pins]
    int num_nodes = out_size;
    int num_pins  = in_sizes[1];

    size_t key4_words = (size_t)((num_pins + 7) / 8);
    size_t need = key4_words * sizeof(uint32_t);

    if (ws_size >= need && num_pins < (1 << 23)) {
        int bits = 32 - __builtin_clz((unsigned)(num_pins - 1));  // ceil(log2)
        int shift = bits > 4 ? bits - 4 : 0;
        uint32_t* key4 = (uint32_t*)d_ws;

        int g1 = (int)((key4_words + NT - 1) / NT);
        build_key4_kernel<<<g1, NT, 0, stream>>>(key, key4, num_pins, shift);

        int g2 = (num_nodes + NPB - 1) / NPB;
        SortNode2Pin_stage_kernel<<<g2, NT, 0, stream>>>(
            starts, n2p, key, key4, (int*)d_out, num_nodes);
    } else {
        int grid = (num_nodes + 255) / 256;
        SortNode2Pin_direct_kernel<<<grid, 256, 0, stream>>>(
            starts, n2p, key, (int*)d_out, num_nodes);
    }
}